// Round 4
// baseline (2528.785 us; speedup 1.0000x reference)
//
#include <hip/hip_runtime.h>
#include <hip/hip_bf16.h>
#include <hip/hip_cooperative_groups.h>

namespace cg = cooperative_groups;

// ---- problem constants (match reference) ----
#define NYI 200
#define NXI 200
#define PMLW 20
#define FDP 2
#define PADW (PMLW + FDP)          // 22
#define NYP (NYI + 2 * PADW)       // 244
#define NXP (NXI + 2 * PADW)       // 244
#define NP  (NYP * NXP)            // 59536
#define NSH 2
#define NRECV 100
#define NTT 120
#define TOTC (NSH * NP)            // 119072

#define DTC   0.0005f
#define RH    0.25f                // 1/DY = 1/DX
#define RH2   0.0625f              // 1/DY^2
#define C1A   (1.0f / 12.0f)
#define C1B   (2.0f / 3.0f)
#define C2A   (1.0f / 12.0f)
#define C2B   (4.0f / 3.0f)

#define MBLOCKS 128
#define MTHREADS 256

// ---- workspace layout (float offsets) ----
#define OFF_MAXV 0
#define OFF_AY   64
#define OFF_BY   (OFF_AY + NYP)
#define OFF_AX   (OFF_BY + NYP)
#define OFF_BX   (OFF_AX + NXP)
#define OFF_V2   (OFF_BX + NXP)
#define OFF_SPV  (OFF_V2 + NP)
#define OFF_F    (OFF_SPV + NP)      // 16 * TOTC floats of fields

__device__ __forceinline__ float cellv(const float* p, int base, int y, int x) {
    if ((unsigned)y >= (unsigned)NYP || (unsigned)x >= (unsigned)NXP) return 0.0f;
    return p[base + y * NXP + x];
}

__global__ void reduce_max_kernel(const float* __restrict__ v, float* __restrict__ out) {
    __shared__ float sm[256];
    float m = 0.0f;
    for (int i = threadIdx.x; i < NYI * NXI; i += 256)
        m = fmaxf(m, v[i]);
    sm[threadIdx.x] = m;
    __syncthreads();
    for (int s = 128; s > 0; s >>= 1) {
        if (threadIdx.x < s) sm[threadIdx.x] = fmaxf(sm[threadIdx.x], sm[threadIdx.x + s]);
        __syncthreads();
    }
    if (threadIdx.x == 0) out[0] = sm[0];
}

__global__ void setup_kernel(const float* __restrict__ v,
                             const float* __restrict__ scat,
                             const float* __restrict__ maxv,
                             float* __restrict__ ay, float* __restrict__ by,
                             float* __restrict__ ax, float* __restrict__ bx,
                             float* __restrict__ v2dt2, float* __restrict__ spv) {
    int gtid = blockIdx.x * blockDim.x + threadIdx.x;
    int nth  = gridDim.x * blockDim.x;

    for (int idx = gtid; idx < NP; idx += nth) {
        int y = idx / NXP;
        int x = idx - y * NXP;
        int yi = min(max(y - PADW, 0), NYI - 1);
        int xi = min(max(x - PADW, 0), NXI - 1);
        float vp = v[yi * NXI + xi];
        v2dt2[idx] = vp * vp * DTC * DTC;
        float sp = 0.0f;
        int ys = y - PADW, xs = x - PADW;
        if (ys >= 0 && ys < NYI && xs >= 0 && xs < NXI)
            sp = scat[ys * NXI + xs];
        spv[idx] = 2.0f * vp * DTC * DTC * sp;
    }

    if (gtid < NYP + NXP) {
        float mv = maxv[0];
        int isY = gtid < NYP;
        int j   = isY ? gtid : gtid - NYP;
        int n   = isY ? NYP : NXP;
        float h = 4.0f;
        float xf = (float)j;
        float lo = (float)(FDP + PMLW);
        float hi = (float)(n - 1 - FDP - PMLW);
        float d1 = fminf(fmaxf((lo - xf) / (float)PMLW, 0.0f), 1.0f);
        float d2 = fminf(fmaxf((xf - hi) / (float)PMLW, 0.0f), 1.0f);
        float d  = fmaxf(d1, d2);
        float sigma = 3.0f * mv * 6.9077552790f / (2.0f * (float)PMLW * h) * d * d;
        float alpha = 6.2831853072f * 25.0f * (1.0f - d);
        float a  = expf(-(sigma + alpha) * DTC);
        float bb = sigma / (sigma + alpha + 1e-9f) * (a - 1.0f);
        if (isY) { ay[j] = a; by[j] = bb; }
        else     { ax[j] = a; bx[j] = bb; }
    }
}

// Fused CPML update for one field at one cell. Recomputes the 4 halo psi_new
// values locally (they are bitwise-identical to the owning threads' values,
// same inlined expression), so no intra-step sync is needed. psi is
// double-buffered (read A / write B); zeta and wf writes are own-cell only.
__device__ __forceinline__ float field_update(
    const float* __restrict__ wf,
    const float* __restrict__ psiyA, float* __restrict__ psiyB,
    const float* __restrict__ psixA, float* __restrict__ psixB,
    float* __restrict__ zety, float* __restrict__ zetx,
    int base, int y, int x, int idx,
    const float* __restrict__ ay, const float* __restrict__ by,
    const float* __restrict__ ax, const float* __restrict__ bx,
    float* __restrict__ w0_out)
{
    float wcol[9], wrow[9];
#pragma unroll
    for (int k = 0; k < 9; ++k) wcol[k] = cellv(wf, base, y - 4 + k, x);
#pragma unroll
    for (int k = 0; k < 9; ++k) wrow[k] = cellv(wf, base, y, x - 4 + k);
    float w0 = wcol[4];
    *w0_out = w0;

    // psi_new at offsets -2..+2 along y (own = o==2)
    float pyn[5];
#pragma unroll
    for (int o = 0; o < 5; ++o) {
        int yy = y - 2 + o;
        if ((unsigned)yy >= (unsigned)NYP) { pyn[o] = 0.0f; continue; }
        float d1 = RH * (C1A * (wcol[o] - wcol[o + 4]) + C1B * (wcol[o + 3] - wcol[o + 1]));
        pyn[o] = ay[yy] * psiyA[base + yy * NXP + x] + by[yy] * d1;
    }
    float pxn[5];
#pragma unroll
    for (int o = 0; o < 5; ++o) {
        int xx = x - 2 + o;
        if ((unsigned)xx >= (unsigned)NXP) { pxn[o] = 0.0f; continue; }
        float d1 = RH * (C1A * (wrow[o] - wrow[o + 4]) + C1B * (wrow[o + 3] - wrow[o + 1]));
        pxn[o] = ax[xx] * psixA[base + y * NXP + xx] + bx[xx] * d1;
    }
    psiyB[idx] = pyn[2];
    psixB[idx] = pxn[2];

    float d1yp = RH * (C1A * (pyn[0] - pyn[4]) + C1B * (pyn[3] - pyn[1]));
    float d1xp = RH * (C1A * (pxn[0] - pxn[4]) + C1B * (pxn[3] - pxn[1]));
    float d2yw = RH2 * (C2B * (wcol[3] + wcol[5]) - C2A * (wcol[2] + wcol[6]) - 2.5f * w0);
    float d2xw = RH2 * (C2B * (wrow[3] + wrow[5]) - C2A * (wrow[2] + wrow[6]) - 2.5f * w0);

    float ty = d2yw + d1yp;
    float tx = d2xw + d1xp;
    float zy = ay[y] * zety[idx] + by[y] * ty;
    float zx = ax[x] * zetx[idx] + bx[x] * tx;
    zety[idx] = zy;
    zetx[idx] = zx;
    return ty + zy + tx + zx;
}

__global__ void __launch_bounds__(MTHREADS)
born_fused(const float* __restrict__ amps,
           const int* __restrict__ sloc,
           const int* __restrict__ rloc,
           const float* __restrict__ ay, const float* __restrict__ by,
           const float* __restrict__ ax, const float* __restrict__ bx,
           const float* __restrict__ v2dt2, const float* __restrict__ spv,
           float* __restrict__ F,
           float* __restrict__ out)
{
    cg::grid_group grid = cg::this_grid();
    const int tid = blockIdx.x * blockDim.x + threadIdx.x;
    const int nth = gridDim.x * blockDim.x;

    float* wfc    = F + 0 * TOTC;   // w(t)
    float* wfp    = F + 1 * TOTC;   // w(t-1) on read, w(t+1) on write
    float* psiyA  = F + 2 * TOTC;   // psi(t) read
    float* psiyB  = F + 3 * TOTC;   // psi(t+1) write
    float* psixA  = F + 4 * TOTC;
    float* psixB  = F + 5 * TOTC;
    float* zety   = F + 6 * TOTC;
    float* zetx   = F + 7 * TOTC;
    float* wfcsc  = F + 8 * TOTC;
    float* wfpsc  = F + 9 * TOTC;
    float* psiyAs = F + 10 * TOTC;
    float* psiyBs = F + 11 * TOTC;
    float* psixAs = F + 12 * TOTC;
    float* psixBs = F + 13 * TOTC;
    float* zetys  = F + 14 * TOTC;
    float* zetxs  = F + 15 * TOTC;

    const int sy0 = sloc[0] + PADW, sx0 = sloc[1] + PADW;
    const int sy1 = sloc[2] + PADW, sx1 = sloc[3] + PADW;

    for (int t = 0; t < NTT; ++t) {
        // record out[:, :, t-1] from w_sc(t) (completed last step; ordered by grid.sync)
        if (t > 0 && tid < NSH * NRECV) {
            int b = tid / NRECV;
            int ry = rloc[tid * 2 + 0] + PADW;
            int rx = rloc[tid * 2 + 1] + PADW;
            out[tid * NTT + (t - 1)] = wfcsc[b * NP + ry * NXP + rx];
        }

        // physical-support box: front moves <= 0.3125 cells/step (vmax<2500)
        int hw = 20 + (int)(0.35f * (float)(t + 1));
        int y0a = max(sy0 - hw, 0), y1a = min(sy0 + hw, NYP - 1);
        int x0a = max(sx0 - hw, 0), x1a = min(sx0 + hw, NXP - 1);
        int bwa = x1a - x0a + 1;
        int cnta = (y1a - y0a + 1) * bwa;
        int y0b = max(sy1 - hw, 0), y1b = min(sy1 + hw, NYP - 1);
        int x0b = max(sx1 - hw, 0), x1b = min(sx1 + hw, NXP - 1);
        int bwb = x1b - x0b + 1;
        int cntb = (y1b - y0b + 1) * bwb;
        int total = cnta + cntb;

        for (int i = tid; i < total; i += nth) {
            int b, y, x;
            if (i < cnta) { b = 0; y = y0a + i / bwa; x = x0a + i % bwa; }
            else { int r = i - cnta; b = 1; y = y0b + r / bwb; x = x0b + r % bwb; }
            int base = b * NP;
            int cell = y * NXP + x;
            int idx  = base + cell;

            float w0, ws0;
            float lap = field_update(wfc, psiyA, psiyB, psixA, psixB,
                                     zety, zetx, base, y, x, idx,
                                     ay, by, ax, bx, &w0);
            float lapsc = field_update(wfcsc, psiyAs, psiyBs, psixAs, psixBs,
                                       zetys, zetxs, base, y, x, idx,
                                       ay, by, ax, bx, &ws0);

            float v2 = v2dt2[cell];
            float wn   = v2 * lap   + 2.0f * w0  - wfp[idx];
            float wnsc = v2 * lapsc + 2.0f * ws0 - wfpsc[idx] + spv[cell] * lap;

            if (b == 0 && y == sy0 && x == sx0) wn += v2 * amps[t];
            if (b == 1 && y == sy1 && x == sx1) wn += v2 * amps[NTT + t];

            wfp[idx]   = wn;
            wfpsc[idx] = wnsc;
        }

        grid.sync();

        // ping-pong swaps (local pointers, uniform across all threads)
        float* tmp;
        tmp = wfc;   wfc = wfp;     wfp = tmp;
        tmp = wfcsc; wfcsc = wfpsc; wfpsc = tmp;
        tmp = psiyA;  psiyA = psiyB;   psiyB = tmp;
        tmp = psixA;  psixA = psixB;   psixB = tmp;
        tmp = psiyAs; psiyAs = psiyBs; psiyBs = tmp;
        tmp = psixAs; psixAs = psixBs; psixBs = tmp;
    }

    // final record: out[:, :, NTT-1] from w_sc(NTT)
    if (tid < NSH * NRECV) {
        int b = tid / NRECV;
        int ry = rloc[tid * 2 + 0] + PADW;
        int rx = rloc[tid * 2 + 1] + PADW;
        out[tid * NTT + (NTT - 1)] = wfcsc[b * NP + ry * NXP + rx];
    }
}

extern "C" void kernel_launch(void* const* d_in, const int* in_sizes, int n_in,
                              void* d_out, int out_size, void* d_ws, size_t ws_size,
                              hipStream_t stream) {
    const float* v    = (const float*)d_in[0];
    const float* scat = (const float*)d_in[1];
    const float* amps = (const float*)d_in[2];
    const int* sloc = (const int*)d_in[3];
    const int* rloc = (const int*)d_in[4];
    float* ws = (float*)d_ws;
    float* out = (float*)d_out;

    float* ay  = ws + OFF_AY;
    float* by  = ws + OFF_BY;
    float* ax  = ws + OFF_AX;
    float* bx  = ws + OFF_BX;
    float* v2  = ws + OFF_V2;
    float* spv = ws + OFF_SPV;
    float* F   = ws + OFF_F;

    // zero the 16 field arrays (ws is poisoned 0xAA before every timed call)
    hipMemsetAsync(F, 0, sizeof(float) * 16 * TOTC, stream);

    reduce_max_kernel<<<1, 256, 0, stream>>>(v, ws + OFF_MAXV);
    setup_kernel<<<(NP + 255) / 256, 256, 0, stream>>>(
        v, scat, ws + OFF_MAXV, ay, by, ax, bx, v2, spv);

    const float* a_amps = amps;
    const int* a_sl = sloc;
    const int* a_rl = rloc;
    float* a_ay = ay; float* a_by = by; float* a_ax = ax; float* a_bx = bx;
    float* a_v2 = v2; float* a_spv = spv; float* a_F = F;
    float* a_out = out;

    void* kargs[] = {&a_amps, &a_sl, &a_rl,
                     &a_ay, &a_by, &a_ax, &a_bx,
                     &a_v2, &a_spv, &a_F, &a_out};

    hipLaunchCooperativeKernel((void*)born_fused,
                               dim3(MBLOCKS), dim3(MTHREADS),
                               kargs, 0, stream);
}

// Round 5
// 1136.719 us; speedup vs baseline: 2.2246x; 2.2246x over previous
//
#include <hip/hip_runtime.h>
#include <hip/hip_bf16.h>

// ---- problem constants (match reference) ----
#define NYI 200
#define NXI 200
#define PMLW 20
#define FDP 2
#define PADW (PMLW + FDP)          // 22
#define NYP (NYI + 2 * PADW)       // 244
#define NXP (NXI + 2 * PADW)       // 244
#define NP  (NYP * NXP)            // 59536
#define NSH 2
#define NRECV 100
#define NTT 120
#define TOTC (NSH * NP)            // 119072

#define DTC   0.0005f
#define RH    0.25f                // 1/DY = 1/DX
#define RH2   0.0625f              // 1/DY^2
#define C1A   (1.0f / 12.0f)
#define C1B   (2.0f / 3.0f)
#define C2A   (1.0f / 12.0f)
#define C2B   (4.0f / 3.0f)

// ---- workspace layout (float offsets) ----
#define OFF_MAXV 0
#define OFF_AY   64
#define OFF_BY   (OFF_AY + NYP)
#define OFF_AX   (OFF_BY + NYP)
#define OFF_BX   (OFF_AX + NXP)
#define OFF_V2   (OFF_BX + NXP)
#define OFF_SPV  (OFF_V2 + NP)
#define OFF_F    (OFF_SPV + NP)      // 16 * TOTC floats of fields

__device__ __forceinline__ float cellv(const float* p, int base, int y, int x) {
    if ((unsigned)y >= (unsigned)NYP || (unsigned)x >= (unsigned)NXP) return 0.0f;
    return p[base + y * NXP + x];
}

__global__ void reduce_max_kernel(const float* __restrict__ v, float* __restrict__ out) {
    __shared__ float sm[256];
    float m = 0.0f;
    for (int i = threadIdx.x; i < NYI * NXI; i += 256)
        m = fmaxf(m, v[i]);
    sm[threadIdx.x] = m;
    __syncthreads();
    for (int s = 128; s > 0; s >>= 1) {
        if (threadIdx.x < s) sm[threadIdx.x] = fmaxf(sm[threadIdx.x], sm[threadIdx.x + s]);
        __syncthreads();
    }
    if (threadIdx.x == 0) out[0] = sm[0];
}

__global__ void setup_kernel(const float* __restrict__ v,
                             const float* __restrict__ scat,
                             const float* __restrict__ maxv,
                             float* __restrict__ ay, float* __restrict__ by,
                             float* __restrict__ ax, float* __restrict__ bx,
                             float* __restrict__ v2dt2, float* __restrict__ spv) {
    int gtid = blockIdx.x * blockDim.x + threadIdx.x;
    int nth  = gridDim.x * blockDim.x;

    for (int idx = gtid; idx < NP; idx += nth) {
        int y = idx / NXP;
        int x = idx - y * NXP;
        int yi = min(max(y - PADW, 0), NYI - 1);
        int xi = min(max(x - PADW, 0), NXI - 1);
        float vp = v[yi * NXI + xi];
        v2dt2[idx] = vp * vp * DTC * DTC;
        float sp = 0.0f;
        int ys = y - PADW, xs = x - PADW;
        if (ys >= 0 && ys < NYI && xs >= 0 && xs < NXI)
            sp = scat[ys * NXI + xs];
        spv[idx] = 2.0f * vp * DTC * DTC * sp;
    }

    if (gtid < NYP + NXP) {
        float mv = maxv[0];
        int isY = gtid < NYP;
        int j   = isY ? gtid : gtid - NYP;
        int n   = isY ? NYP : NXP;
        float h = 4.0f;
        float xf = (float)j;
        float lo = (float)(FDP + PMLW);
        float hi = (float)(n - 1 - FDP - PMLW);
        float d1 = fminf(fmaxf((lo - xf) / (float)PMLW, 0.0f), 1.0f);
        float d2 = fminf(fmaxf((xf - hi) / (float)PMLW, 0.0f), 1.0f);
        float d  = fmaxf(d1, d2);
        float sigma = 3.0f * mv * 6.9077552790f / (2.0f * (float)PMLW * h) * d * d;
        float alpha = 6.2831853072f * 25.0f * (1.0f - d);
        float a  = expf(-(sigma + alpha) * DTC);
        float bb = sigma / (sigma + alpha + 1e-9f) * (a - 1.0f);
        if (isY) { ay[j] = a; by[j] = bb; }
        else     { ax[j] = a; bx[j] = bb; }
    }
}

// Fused CPML update for one field at one cell. Recomputes the 4 halo psi_new
// values locally (bitwise-identical to the owning threads' values), so no
// intra-step sync is needed. psi is double-buffered (read A / write B);
// zeta and wf writes are own-cell only.  [validated R4: absmax == split-kernel]
__device__ __forceinline__ float field_update(
    const float* __restrict__ wf,
    const float* __restrict__ psiyA, float* __restrict__ psiyB,
    const float* __restrict__ psixA, float* __restrict__ psixB,
    float* __restrict__ zety, float* __restrict__ zetx,
    int base, int y, int x, int idx,
    const float* __restrict__ ay, const float* __restrict__ by,
    const float* __restrict__ ax, const float* __restrict__ bx,
    float* __restrict__ w0_out)
{
    float wcol[9], wrow[9];
#pragma unroll
    for (int k = 0; k < 9; ++k) wcol[k] = cellv(wf, base, y - 4 + k, x);
#pragma unroll
    for (int k = 0; k < 9; ++k) wrow[k] = cellv(wf, base, y, x - 4 + k);
    float w0 = wcol[4];
    *w0_out = w0;

    float pyn[5];
#pragma unroll
    for (int o = 0; o < 5; ++o) {
        int yy = y - 2 + o;
        if ((unsigned)yy >= (unsigned)NYP) { pyn[o] = 0.0f; continue; }
        float d1 = RH * (C1A * (wcol[o] - wcol[o + 4]) + C1B * (wcol[o + 3] - wcol[o + 1]));
        pyn[o] = ay[yy] * psiyA[base + yy * NXP + x] + by[yy] * d1;
    }
    float pxn[5];
#pragma unroll
    for (int o = 0; o < 5; ++o) {
        int xx = x - 2 + o;
        if ((unsigned)xx >= (unsigned)NXP) { pxn[o] = 0.0f; continue; }
        float d1 = RH * (C1A * (wrow[o] - wrow[o + 4]) + C1B * (wrow[o + 3] - wrow[o + 1]));
        pxn[o] = ax[xx] * psixA[base + y * NXP + xx] + bx[xx] * d1;
    }
    psiyB[idx] = pyn[2];
    psixB[idx] = pxn[2];

    float d1yp = RH * (C1A * (pyn[0] - pyn[4]) + C1B * (pyn[3] - pyn[1]));
    float d1xp = RH * (C1A * (pxn[0] - pxn[4]) + C1B * (pxn[3] - pxn[1]));
    float d2yw = RH2 * (C2B * (wcol[3] + wcol[5]) - C2A * (wcol[2] + wcol[6]) - 2.5f * w0);
    float d2xw = RH2 * (C2B * (wrow[3] + wrow[5]) - C2A * (wrow[2] + wrow[6]) - 2.5f * w0);

    float ty = d2yw + d1yp;
    float tx = d2xw + d1xp;
    float zy = ay[y] * zety[idx] + by[y] * ty;
    float zx = ax[x] * zetx[idx] + bx[x] * tx;
    zety[idx] = zy;
    zetx[idx] = zx;
    return ty + zy + tx + zx;
}

// One full time step (both fields) + record of previous step's receivers.
// Launch-ordered: no intra-kernel grid sync needed (halo recompute).
__global__ void __launch_bounds__(256)
born_step(int t, int hw,
          const float* __restrict__ wfc, float* __restrict__ wfp,
          const float* __restrict__ psiyA, float* __restrict__ psiyB,
          const float* __restrict__ psixA, float* __restrict__ psixB,
          float* __restrict__ zety, float* __restrict__ zetx,
          const float* __restrict__ wfcsc, float* __restrict__ wfpsc,
          const float* __restrict__ psiyAs, float* __restrict__ psiyBs,
          const float* __restrict__ psixAs, float* __restrict__ psixBs,
          float* __restrict__ zetys, float* __restrict__ zetxs,
          const float* __restrict__ ay, const float* __restrict__ by,
          const float* __restrict__ ax, const float* __restrict__ bx,
          const float* __restrict__ v2dt2, const float* __restrict__ spv,
          const float* __restrict__ amps, const int* __restrict__ sloc,
          const int* __restrict__ rloc, float* __restrict__ out)
{
    const int tid = blockIdx.x * blockDim.x + threadIdx.x;

    // record out[:, :, t-1] from w_sc(t) (written by previous launch)
    if (t > 0 && tid < NSH * NRECV) {
        int b = tid / NRECV;
        int ry = rloc[tid * 2 + 0] + PADW;
        int rx = rloc[tid * 2 + 1] + PADW;
        out[tid * NTT + (t - 1)] = wfcsc[b * NP + ry * NXP + rx];
    }

    const int sy0 = sloc[0] + PADW, sx0 = sloc[1] + PADW;
    const int sy1 = sloc[2] + PADW, sx1 = sloc[3] + PADW;

    // physical-support boxes (front <= 0.3125 cells/step, vmax < 2500)
    int y0a = max(sy0 - hw, 0), y1a = min(sy0 + hw, NYP - 1);
    int x0a = max(sx0 - hw, 0), x1a = min(sx0 + hw, NXP - 1);
    int bwa = x1a - x0a + 1;
    int cnta = (y1a - y0a + 1) * bwa;
    int y0b = max(sy1 - hw, 0), y1b = min(sy1 + hw, NYP - 1);
    int x0b = max(sx1 - hw, 0), x1b = min(sx1 + hw, NXP - 1);
    int bwb = x1b - x0b + 1;
    int cntb = (y1b - y0b + 1) * bwb;
    int total = cnta + cntb;

    if (tid >= total) return;

    int b, y, x;
    if (tid < cnta) { b = 0; y = y0a + tid / bwa; x = x0a + tid % bwa; }
    else { int r = tid - cnta; b = 1; y = y0b + r / bwb; x = x0b + r % bwb; }
    int base = b * NP;
    int cell = y * NXP + x;
    int idx  = base + cell;

    float w0, ws0;
    float lap = field_update(wfc, psiyA, psiyB, psixA, psixB,
                             zety, zetx, base, y, x, idx,
                             ay, by, ax, bx, &w0);
    float lapsc = field_update(wfcsc, psiyAs, psiyBs, psixAs, psixBs,
                               zetys, zetxs, base, y, x, idx,
                               ay, by, ax, bx, &ws0);

    float v2 = v2dt2[cell];
    float wn   = v2 * lap   + 2.0f * w0  - wfp[idx];
    float wnsc = v2 * lapsc + 2.0f * ws0 - wfpsc[idx] + spv[cell] * lap;

    if (b == 0 && y == sy0 && x == sx0) wn += v2 * amps[t];
    if (b == 1 && y == sy1 && x == sx1) wn += v2 * amps[NTT + t];

    wfp[idx]   = wn;
    wfpsc[idx] = wnsc;
}

__global__ void record_kernel(const float* __restrict__ wfcsc,
                              const int* __restrict__ rloc,
                              float* __restrict__ out) {
    int idx = threadIdx.x;
    if (idx < NSH * NRECV) {
        int b = idx / NRECV;
        int ry = rloc[idx * 2 + 0] + PADW;
        int rx = rloc[idx * 2 + 1] + PADW;
        out[idx * NTT + (NTT - 1)] = wfcsc[b * NP + ry * NXP + rx];
    }
}

extern "C" void kernel_launch(void* const* d_in, const int* in_sizes, int n_in,
                              void* d_out, int out_size, void* d_ws, size_t ws_size,
                              hipStream_t stream) {
    const float* v    = (const float*)d_in[0];
    const float* scat = (const float*)d_in[1];
    const float* amps = (const float*)d_in[2];
    const int* sloc = (const int*)d_in[3];
    const int* rloc = (const int*)d_in[4];
    float* ws = (float*)d_ws;
    float* out = (float*)d_out;

    float* ay  = ws + OFF_AY;
    float* by  = ws + OFF_BY;
    float* ax  = ws + OFF_AX;
    float* bx  = ws + OFF_BX;
    float* v2  = ws + OFF_V2;
    float* spv = ws + OFF_SPV;
    float* F   = ws + OFF_F;

    float* wfc    = F + 0 * TOTC;
    float* wfp    = F + 1 * TOTC;
    float* psiyA  = F + 2 * TOTC;
    float* psiyB  = F + 3 * TOTC;
    float* psixA  = F + 4 * TOTC;
    float* psixB  = F + 5 * TOTC;
    float* zety   = F + 6 * TOTC;
    float* zetx   = F + 7 * TOTC;
    float* wfcsc  = F + 8 * TOTC;
    float* wfpsc  = F + 9 * TOTC;
    float* psiyAs = F + 10 * TOTC;
    float* psiyBs = F + 11 * TOTC;
    float* psixAs = F + 12 * TOTC;
    float* psixBs = F + 13 * TOTC;
    float* zetys  = F + 14 * TOTC;
    float* zetxs  = F + 15 * TOTC;

    // zero the 16 field arrays (ws is poisoned 0xAA before every timed call)
    hipMemsetAsync(F, 0, sizeof(float) * 16 * TOTC, stream);

    reduce_max_kernel<<<1, 256, 0, stream>>>(v, ws + OFF_MAXV);
    setup_kernel<<<(NP + 255) / 256, 256, 0, stream>>>(
        v, scat, ws + OFF_MAXV, ay, by, ax, bx, v2, spv);

    for (int t = 0; t < NTT; ++t) {
        int hw = 20 + (int)(0.35f * (float)(t + 1));
        int side = 2 * hw + 1; if (side > NYP) side = NYP;
        int total_max = 2 * side * side;
        int blocks = (total_max + 255) / 256;

        born_step<<<blocks, 256, 0, stream>>>(
            t, hw,
            wfc, wfp, psiyA, psiyB, psixA, psixB, zety, zetx,
            wfcsc, wfpsc, psiyAs, psiyBs, psixAs, psixBs, zetys, zetxs,
            ay, by, ax, bx, v2, spv, amps, sloc, rloc, out);

        float* tmp;
        tmp = wfc;    wfc = wfp;       wfp = tmp;
        tmp = wfcsc;  wfcsc = wfpsc;   wfpsc = tmp;
        tmp = psiyA;  psiyA = psiyB;   psiyB = tmp;
        tmp = psixA;  psixA = psixB;   psixB = tmp;
        tmp = psiyAs; psiyAs = psiyBs; psiyBs = tmp;
        tmp = psixAs; psixAs = psixBs; psixBs = tmp;
    }
    record_kernel<<<1, 256, 0, stream>>>(wfcsc, rloc, out);
}